// Round 11
// baseline (222.374 us; speedup 1.0000x reference)
//
#include <hip/hip_runtime.h>
#include <math.h>

#define HIDDEN 64
#define SEQ 128
#define BATCH 64
#define NPTS (BATCH * SEQ)   // 8192
#define TMAXV 20.0f
#define L2E 1.4426950408889634f
#define LN2 0.6931471805599453f

typedef float v2f __attribute__((ext_vector_type(2)));
typedef float v4f __attribute__((ext_vector_type(4)));

__device__ __forceinline__ float fexp2(float x) { return __builtin_amdgcn_exp2f(x); }
__device__ __forceinline__ float flog2(float x) { return __builtin_amdgcn_logf(x); }
__device__ __forceinline__ float frcp(float x)  { return __builtin_amdgcn_rcpf(x); }
__device__ __forceinline__ float fsigmoid(float x) { return frcp(1.0f + fexp2(-x * L2E)); }
__device__ __forceinline__ float ftanh(float x)    { return 1.0f - 2.0f * frcp(1.0f + fexp2(2.0f * x * L2E)); }

// ---- DPP wave64 sum: VALU-pipe cross-lane (no LDS round trips). Result uniform.
template <int CTRL>
__device__ __forceinline__ float dpp_mov(float x) {
    int r = __builtin_amdgcn_update_dpp(0, __float_as_int(x), CTRL, 0xf, 0xf, false);
    return __int_as_float(r);
}
__device__ __forceinline__ float wave_sum_dpp(float x) {
    x += dpp_mov<0x111>(x);   // row_shr:1
    x += dpp_mov<0x112>(x);   // row_shr:2
    x += dpp_mov<0x114>(x);   // row_shr:4
    x += dpp_mov<0x118>(x);   // row_shr:8  -> lane 16r+15 = row sum
    x += dpp_mov<0x142>(x);   // row_bcast:15
    x += dpp_mov<0x143>(x);   // row_bcast:31 -> lane 63 = total
    return __int_as_float(__builtin_amdgcn_readlane(__float_as_int(x), 63));
}

__device__ __forceinline__ float wave_sum_shfl(float v) {
    v += __shfl_xor(v, 1);  v += __shfl_xor(v, 2);  v += __shfl_xor(v, 4);
    v += __shfl_xor(v, 8);  v += __shfl_xor(v, 16); v += __shfl_xor(v, 32);
    return v;
}

// Blocks [0,64): LSTM rollout, ONE WAVE per batch (64 threads). Lane h owns all
// 4 gate rows {h,64+h,128+h,192+h} -> gates LANE-LOCAL: no act exchange, no
// barrier. Weights FORCED register-resident (256 VGPRs):
//   stage global->LDS -> lgkmcnt+mem-clobber (blocks store-to-load forwarding,
//   so remat source = the LDS load) -> readback to regs -> VOLATILE-STORE ZEROS
//   over the whole staging region. Any reload now observes zeros -> reload is
//   not semantics-preserving -> compiler MUST keep the values in registers
//   (budget 512 via __launch_bounds__(64,1); ~350 live, no spill pressure).
//   NO in-loop memory clobbers (r10's mistake: they invite per-step re-reads).
// Blocks [64,576): expert-expert MMD, one wave each (r10-verified partial sums).
__global__ __launch_bounds__(64, 1) void gen_and_ee(
    const float* __restrict__ upool,   // [B,S]
    const float* __restrict__ texp,    // [B,S]
    const float* __restrict__ Wih,     // [256]
    const float* __restrict__ Whh,     // [256,64]
    const float* __restrict__ bih,     // [256]
    const float* __restrict__ bhh,     // [256]
    const float* __restrict__ Vw,      // [64]
    const float* __restrict__ Vb,      // [1]
    float* __restrict__ tl,            // [NPTS] workspace
    float* __restrict__ out)           // [1] loss accumulator
{
    // [0,16384)      floats: weight staging (zeroed after readback) / EE qbuf
    // [16384,16448)  hx_s[64]
    // [16448,16576)  lu_s[128]
    // [16576,16832)  pad (build canary: LDS size != r10's 66560)
    __shared__ __align__(16) float smem[16832];

    const int bid = blockIdx.x;
    const int tid = threadIdx.x;      // 0..63

    if (bid < BATCH) {
        const int h = tid;
        float* hx_s = smem + 16384;
        float* lu_s = smem + 16448;

        // ---- stage all 4 gate rows into LDS: [gate*16+k][lane] float4 ----
        float4* st = (float4*)smem;
        {
            const float4* r0 = (const float4*)(Whh + (h)       * 64);
            const float4* r1 = (const float4*)(Whh + (64 + h)  * 64);
            const float4* r2 = (const float4*)(Whh + (128 + h) * 64);
            const float4* r3 = (const float4*)(Whh + (192 + h) * 64);
            #pragma unroll
            for (int k = 0; k < 16; ++k) {
                st[(k)      * 64 + h] = r0[k];
                st[(16 + k) * 64 + h] = r1[k];
                st[(32 + k) * 64 + h] = r2[k];
                st[(48 + k) * 64 + h] = r3[k];
            }
        }
        // publish; opaque mem op blocks store->load value forwarding
        asm volatile("s_waitcnt lgkmcnt(0)" ::: "memory");

        // ---- readback to 256 VGPRs ----
        v2f wi[32], wf[32], wg[32], wo[32];
        #pragma unroll
        for (int k = 0; k < 16; ++k) {
            float4 v0 = st[(k)      * 64 + h];
            float4 v1 = st[(16 + k) * 64 + h];
            float4 v2_ = st[(32 + k) * 64 + h];
            float4 v3 = st[(48 + k) * 64 + h];
            wi[2*k] = (v2f){v0.x, v0.y}; wi[2*k+1] = (v2f){v0.z, v0.w};
            wf[2*k] = (v2f){v1.x, v1.y}; wf[2*k+1] = (v2f){v1.z, v1.w};
            wg[2*k] = (v2f){v2_.x, v2_.y}; wg[2*k+1] = (v2f){v2_.z, v2_.w};
            wo[2*k] = (v2f){v3.x, v3.y}; wo[2*k+1] = (v2f){v3.z, v3.w};
        }
        asm volatile("s_waitcnt lgkmcnt(0)" ::: "memory");   // readback done

        // ---- destroy the staging data (volatile: cannot be DCE'd). After
        // this, re-loading the weights would read zeros -> residency forced.
        {
            volatile v4f* vz = (volatile v4f*)smem;
            v4f z = (v4f){0.f, 0.f, 0.f, 0.f};
            #pragma unroll
            for (int i = 0; i < 64; ++i) vz[i * 64 + h] = z;
        }
        asm volatile("s_waitcnt lgkmcnt(0)" ::: "memory");

        const float bi_ = bih[h]       + bhh[h];
        const float bf_ = bih[64 + h]  + bhh[64 + h];
        const float bg_ = bih[128 + h] + bhh[128 + h];
        const float bo_ = bih[192 + h] + bhh[192 + h];
        const float wii = Wih[h], wif = Wih[64 + h], wig = Wih[128 + h], wio = Wih[192 + h];
        const float vw = Vw[h];
        const float vb = Vb[0];

        lu_s[h]      = -flog2(upool[bid * SEQ + h]) * LN2;
        lu_s[64 + h] = -flog2(upool[bid * SEQ + 64 + h]) * LN2;
        hx_s[h] = 0.0f;
        float cx = 0.0f;

        // step 0: hx = 0 -> sigma = elu(Vb)+1 (uniform)
        float sg0 = (vb > 0.0f) ? (vb + 1.0f) : fexp2(vb * L2E);
        float cum = lu_s[0] * frcp(sg0);
        float keep0 = (h == 0) ? cum : 0.0f;
        float keep1 = 0.0f;

        #pragma unroll 1
        for (int s = 0; s < SEQ - 1; ++s) {
            float lunext = lu_s[s + 1];
            const float4* h4 = (const float4*)hx_s;   // broadcast b128 reads
            // accumulation order bit-identical to r1/r2/r10 (harness-verified)
            v2f i0={0.f,0.f}, i1={0.f,0.f}, i2={0.f,0.f}, i3={0.f,0.f};
            v2f f0={0.f,0.f}, f1={0.f,0.f}, f2={0.f,0.f}, f3={0.f,0.f};
            v2f g0={0.f,0.f}, g1={0.f,0.f}, g2={0.f,0.f}, g3={0.f,0.f};
            v2f o0={0.f,0.f}, o1={0.f,0.f}, o2={0.f,0.f}, o3={0.f,0.f};
            #pragma unroll
            for (int k = 0; k < 16; k += 2) {
                float4 va4 = h4[k];
                float4 vb4 = h4[k + 1];
                v2f x0 = (v2f){va4.x, va4.y};
                v2f x1 = (v2f){va4.z, va4.w};
                v2f x2 = (v2f){vb4.x, vb4.y};
                v2f x3 = (v2f){vb4.z, vb4.w};
                i0 += wi[2*k] * x0; i1 += wi[2*k+1] * x1; i2 += wi[2*k+2] * x2; i3 += wi[2*k+3] * x3;
                f0 += wf[2*k] * x0; f1 += wf[2*k+1] * x1; f2 += wf[2*k+2] * x2; f3 += wf[2*k+3] * x3;
                g0 += wg[2*k] * x0; g1 += wg[2*k+1] * x1; g2 += wg[2*k+2] * x2; g3 += wg[2*k+3] * x3;
                o0 += wo[2*k] * x0; o1 += wo[2*k+1] * x1; o2 += wo[2*k+2] * x2; o3 += wo[2*k+3] * x3;
            }
            v2f ia = (i0 + i1) + (i2 + i3);
            v2f fa = (f0 + f1) + (f2 + f3);
            v2f ga = (g0 + g1) + (g2 + g3);
            v2f oa = (o0 + o1) + (o2 + o3);
            float gi = (ia.x + ia.y) + bi_ + cum * wii;
            float gf = (fa.x + fa.y) + bf_ + cum * wif;
            float gg = (ga.x + ga.y) + bg_ + cum * wig;
            float go = (oa.x + oa.y) + bo_ + cum * wio;

            float ig = fsigmoid(gi);
            float fg = fsigmoid(gf);
            float gt = ftanh(gg);
            float og = fsigmoid(go);
            cx = fg * cx + ig * gt;
            float hx = og * ftanh(cx);
            hx_s[h] = hx;                          // in-wave lgkmcnt ordering only

            float tot = wave_sum_dpp(hx * vw);     // overlaps hx LDS round-trip
            float xx  = tot + vb;
            float sg  = (xx > 0.0f) ? (xx + 1.0f) : fexp2(xx * L2E);
            cum += lunext * frcp(sg);

            const int sp = s + 1;
            keep0 = (h == sp) ? cum : keep0;       // sp>=64 never matches h<64
            keep1 = (h == sp - 64) ? cum : keep1;  // sp<64 -> negative, no match
        }
        tl[bid * SEQ + h]      = keep0;
        tl[bid * SEQ + 64 + h] = keep1;
    } else {
        // ---------------- expert-expert MMD term (one wave per block) --------
        const int eb = bid - BATCH;      // 0..511
        const int pc = eb & 127;         // p-chunk (64 points)
        const int qs = eb >> 7;          // q-split (2048 points)

        float2* qbuf = (float2*)smem;    // [2048], aliases stage pool

        const int p = pc * 64 + tid;
        const float tp = texp[p];
        const float mp = (tp < TMAXV && tp > 0.0f) ? 1.0f : 0.0f;

        const int q0 = qs * 2048;
        for (int i = tid; i < 2048; i += 64) {
            float tq = texp[q0 + i];
            float mq = (tq < TMAXV && tq > 0.0f) ? 1.0f : 0.0f;
            qbuf[i] = make_float2(tq, mq);
        }
        __syncthreads();

        float acc = 0.0f;
        #pragma unroll 4
        for (int i = 0; i < 2048; ++i) {
            float2 qq = qbuf[i];
            float d = tp - qq.x;
            acc = fmaf(qq.y, fexp2(d * d * (-L2E)), acc);
        }
        acc *= mp;
        acc = wave_sum_shfl(acc);        // same xor order -> same wave sums
        if (tid == 0) atomicAdd(out, acc);
    }
}

// ll + le terms. Grid (32, 16): 32 p-chunks of 256 x 16 q-splits of 512.
__global__ __launch_bounds__(256) void ll_le(
    const float* __restrict__ texp,
    const float* __restrict__ tl,
    float* __restrict__ out)
{
    __shared__ __align__(16) float4 qbuf[512];
    __shared__ float red[4];

    const int pc = blockIdx.x;
    const int qs = blockIdx.y;
    const int tid = threadIdx.x;

    const int p = pc * 256 + tid;
    const float tlp = tl[p];
    const float mlp = (tlp < TMAXV && tlp > 0.0f) ? 1.0f : 0.0f;

    const int q0 = qs * 512;
    for (int i = tid; i < 512; i += 256) {
        float tq = tl[q0 + i];
        float mq = (tq < TMAXV && tq > 0.0f) ? 1.0f : 0.0f;
        float te = texp[q0 + i];
        float me = (te < TMAXV && te > 0.0f) ? 1.0f : 0.0f;
        qbuf[i] = make_float4(tq, mq, te, me);
    }
    __syncthreads();

    float val = 0.0f;
    // learner times are cumsum of Exp(1) increments: most p-points exceed T_MAX;
    // fully-masked waves skip the whole q-loop (wave-uniform branch).
    if (__ballot(mlp != 0.0f) != 0ULL) {
        float a_ll = 0.0f, a_le = 0.0f;
        #pragma unroll 4
        for (int i = 0; i < 512; ++i) {
            float4 q = qbuf[i];
            float d1 = tlp - q.x;
            a_ll = fmaf(q.y, fexp2(d1 * d1 * (-L2E)), a_ll);
            float d2 = tlp - q.z;
            a_le = fmaf(q.w, fexp2(d2 * d2 * (-L2E)), a_le);
        }
        val = mlp * (a_ll - 2.0f * a_le);
    }

    val = wave_sum_shfl(val);
    if ((tid & 63) == 0) red[tid >> 6] = val;
    __syncthreads();
    if (tid == 0) atomicAdd(out, red[0] + red[1] + red[2] + red[3]);
}

extern "C" void kernel_launch(void* const* d_in, const int* in_sizes, int n_in,
                              void* d_out, int out_size, void* d_ws, size_t ws_size,
                              hipStream_t stream) {
    const float* upool = (const float*)d_in[0];
    const float* texp  = (const float*)d_in[1];
    const float* Wih   = (const float*)d_in[2];
    const float* Whh   = (const float*)d_in[3];
    const float* bih   = (const float*)d_in[4];
    const float* bhh   = (const float*)d_in[5];
    const float* Vw    = (const float*)d_in[6];
    const float* Vb    = (const float*)d_in[7];
    float* out = (float*)d_out;
    float* tl  = (float*)d_ws;   // 8192 floats = 32 KB

    hipMemsetAsync(out, 0, sizeof(float), stream);
    hipLaunchKernelGGL(gen_and_ee, dim3(BATCH + 512), dim3(64), 0, stream,
                       upool, texp, Wih, Whh, bih, bhh, Vw, Vb, tl, out);
    hipLaunchKernelGGL(ll_le, dim3(32, 16), dim3(256), 0, stream, texp, tl, out);
}

// Round 12
// 159.048 us; speedup vs baseline: 1.3982x; 1.3982x over previous
//
#include <hip/hip_runtime.h>
#include <math.h>

#define HIDDEN 64
#define SEQ 128
#define BATCH 64
#define NPTS (BATCH * SEQ)   // 8192
#define TMAXV 20.0f
#define L2E 1.4426950408889634f
#define LN2 0.6931471805599453f

typedef float v2f __attribute__((ext_vector_type(2)));

__device__ __forceinline__ float fexp2(float x) { return __builtin_amdgcn_exp2f(x); }
__device__ __forceinline__ float flog2(float x) { return __builtin_amdgcn_logf(x); }
__device__ __forceinline__ float frcp(float x)  { return __builtin_amdgcn_rcpf(x); }
__device__ __forceinline__ float fsigmoid(float x) { return frcp(1.0f + fexp2(-x * L2E)); }
__device__ __forceinline__ float ftanh(float x)    { return 1.0f - 2.0f * frcp(1.0f + fexp2(2.0f * x * L2E)); }

// Raw barrier: orders LDS only (lgkmcnt), does NOT drain vmcnt.
__device__ __forceinline__ void barrier_lds_only() {
    asm volatile("s_waitcnt lgkmcnt(0)" ::: "memory");
    __builtin_amdgcn_s_barrier();
}

// ---- DPP wave64 sum: VALU-pipe cross-lane (no LDS round trips). Result uniform.
template <int CTRL>
__device__ __forceinline__ float dpp_mov(float x) {
    int r = __builtin_amdgcn_update_dpp(0, __float_as_int(x), CTRL, 0xf, 0xf, false);
    return __int_as_float(r);
}
__device__ __forceinline__ float wave_sum_dpp(float x) {
    x += dpp_mov<0x111>(x);   // row_shr:1
    x += dpp_mov<0x112>(x);   // row_shr:2
    x += dpp_mov<0x114>(x);   // row_shr:4
    x += dpp_mov<0x118>(x);   // row_shr:8  -> lane 16r+15 = row sum
    x += dpp_mov<0x142>(x);   // row_bcast:15
    x += dpp_mov<0x143>(x);   // row_bcast:31 -> lane 63 = total
    return __int_as_float(__builtin_amdgcn_readlane(__float_as_int(x), 63));
}

__device__ __forceinline__ float wave_sum_shfl(float v) {
    v += __shfl_xor(v, 1);  v += __shfl_xor(v, 2);  v += __shfl_xor(v, 4);
    v += __shfl_xor(v, 8);  v += __shfl_xor(v, 16); v += __shfl_xor(v, 32);
    return v;
}

// Blocks [0,64): LSTM rollout, one batch per block, 256 threads (thread j = gate-row j).
// r3 structure (67.7us, proven) with HYBRID weight delivery:
//   - chunks 0-7 (32 floats/thread) REGISTER-RESIDENT via the r9-proven recipe:
//     stage global->LDS (conflict-free layout) -> __syncthreads (kills
//     store-to-load forwarding; value source = LDS) -> readback -> the staging
//     region ALIASES act_s (overwritten every step by other threads) -> any
//     reload after the pre-loop barrier is illegal -> 32 floats stay in VGPRs
//     (r9: exactly this held at VGPR=52; no pressure at 32 floats).
//   - chunks 8-15 streamed from global per step (as r3) -- working set now
//     32 KB = L1-sized -> steady-state L1 hits (r3's 64 KB was 50% L2 misses).
// Blocks [64,192): expert-expert MMD term (r3-identical).
__global__ __launch_bounds__(256) void gen_and_ee(
    const float* __restrict__ upool,   // [B,S]
    const float* __restrict__ texp,    // [B,S]
    const float* __restrict__ Wih,     // [256]
    const float* __restrict__ Whh,     // [256,64]
    const float* __restrict__ bih,     // [256]
    const float* __restrict__ bhh,     // [256]
    const float* __restrict__ Vw,      // [64]
    const float* __restrict__ Vb,      // [1]
    float* __restrict__ tl,            // [NPTS] workspace
    float* __restrict__ out)           // [1] loss accumulator
{
    // [0,8192)      staging pool: w_stage[8][256]float4 (32 KB).
    //               act_s[2][256] = floats [0,512) ALIASES it.   [LSTM]
    //               qbuf float2[2048] = floats [0,4096) ALIASES it. [EE]
    // [8192,8448)   hx_s[4][64]
    // [8448,8576)   lu_s[128]
    __shared__ __align__(16) float smem[8576];

    const int bid = blockIdx.x;
    const int tid = threadIdx.x;

    if (bid < BATCH) {
        const int h  = tid & 63;
        const int wv = tid >> 6;

        float* act  = smem;                     // [2][256]
        float* hx_s = smem + 8192 + wv * 64;    // this wave's replica
        float* lu_s = smem + 8448;

        // ---- stage chunks 0-7 into LDS (conflict-free: st[k*256+tid]) ----
        float4* st = (float4*)smem;
        const float4* wrow = (const float4*)(Whh + tid * 64);
        #pragma unroll
        for (int k = 0; k < 8; ++k) st[k * 256 + tid] = wrow[k];
        __syncthreads();                        // kills store->load forwarding

        // ---- readback chunks 0-7 to 32 resident VGPRs ----
        v2f wr[16];
        #pragma unroll
        for (int k = 0; k < 8; ++k) {
            float4 v = st[k * 256 + tid];
            wr[2 * k]     = (v2f){v.x, v.y};
            wr[2 * k + 1] = (v2f){v.z, v.w};
        }

        const float bias = bih[tid] + bhh[tid];
        const float wih  = Wih[tid];
        const float vw   = Vw[h];      // all waves: redundant sigma reduction
        const float vb   = Vb[0];

        if (tid < SEQ) lu_s[tid] = -flog2(upool[bid * SEQ + tid]) * LN2;
        hx_s[h] = 0.0f;                // every wave zeroes its own replica
        float cx = 0.0f;
        barrier_lds_only();            // after this, act stores may clobber staging
                                       // -> readback cannot be re-executed

        // step 0: hx = 0 -> sigma = elu(Vb)+1 (uniform)
        float sg0 = (vb > 0.0f) ? (vb + 1.0f) : fexp2(vb * L2E);
        float cum = lu_s[0] * frcp(sg0);
        float keep = (tid == 0) ? cum : 0.0f;   // thread t keeps cum of step t

        const float4* wg = ((const float4*)(Whh + tid * 64)) + 8;  // streamed half

        #pragma unroll 1
        for (int s = 0; s < SEQ - 1; ++s) {
            // streamed half (chunks 8-15): 32 KB/CU working set -> L1 hits
            float4 gw[8];
            #pragma unroll
            for (int k = 0; k < 8; ++k) gw[k] = wg[k];

            // gate-row dot hx, from this wave's private replica (broadcast b128)
            const float4* h4 = (const float4*)(smem + 8192 + wv * 64);
            v2f a0 = {0.f, 0.f}, a1 = {0.f, 0.f}, a2 = {0.f, 0.f}, a3 = {0.f, 0.f};
            #pragma unroll
            for (int k = 0; k < 16; k += 2) {
                float4 va = h4[k];
                float4 vbq = h4[k + 1];
                v2f wAxy, wAzw, wBxy, wBzw;
                if (k < 8) {
                    wAxy = wr[2 * k];     wAzw = wr[2 * k + 1];
                    wBxy = wr[2 * k + 2]; wBzw = wr[2 * k + 3];
                } else {
                    float4 wA = gw[k - 8];
                    float4 wB = gw[k - 7];
                    wAxy = (v2f){wA.x, wA.y}; wAzw = (v2f){wA.z, wA.w};
                    wBxy = (v2f){wB.x, wB.y}; wBzw = (v2f){wB.z, wB.w};
                }
                // identical FMA pairing/order as r3 (bit-exact)
                a0 = a0 + wAxy * (v2f){va.x, va.y};
                a1 = a1 + wAzw * (v2f){va.z, va.w};
                a2 = a2 + wBxy * (v2f){vbq.x, vbq.y};
                a3 = a3 + wBzw * (v2f){vbq.z, vbq.w};
            }
            v2f aa = (a0 + a1) + (a2 + a3);
            float g = (aa.x + aa.y) + bias + cum * wih;
            float a = (wv == 2) ? ftanh(g) : fsigmoid(g);
            act[(s & 1) * 256 + tid] = a;
            barrier_lds_only();        // the ONLY barrier per step; no vmcnt drain

            // redundant cell update in every wave (bit-identical across waves)
            float ig = act[(s & 1) * 256 + h];
            float fg = act[(s & 1) * 256 + 64 + h];
            float gg = act[(s & 1) * 256 + 128 + h];
            float og = act[(s & 1) * 256 + 192 + h];
            cx = fg * cx + ig * gg;
            float hx = og * ftanh(cx);
            hx_s[h] = hx;              // own replica; in-wave lgkmcnt ordering only

            float tot = wave_sum_dpp(hx * vw);
            float xx  = tot + vb;
            float sg  = (xx > 0.0f) ? (xx + 1.0f) : fexp2(xx * L2E);
            cum += lu_s[s + 1] * frcp(sg);

            keep = (tid == s + 1) ? cum : keep;   // threads 128..255 never match
        }
        if (tid < SEQ) tl[bid * SEQ + tid] = keep;
    } else {
        // ---------------- expert-expert MMD term (r3-identical) ----------------
        const int eb = bid - BATCH;      // 0..127
        const int pc = eb & 31;          // p-chunk (256 points)
        const int qs = eb >> 5;          // q-split (2048 points)

        float2* qbuf = (float2*)smem;    // [2048], aliases staging pool

        const int p = pc * 256 + tid;
        const float tp = texp[p];
        const float mp = (tp < TMAXV && tp > 0.0f) ? 1.0f : 0.0f;

        const int q0 = qs * 2048;
        for (int i = tid; i < 2048; i += 256) {
            float tq = texp[q0 + i];
            float mq = (tq < TMAXV && tq > 0.0f) ? 1.0f : 0.0f;
            qbuf[i] = make_float2(tq, mq);
        }
        __syncthreads();

        float acc = 0.0f;
        #pragma unroll 4
        for (int i = 0; i < 2048; ++i) {
            float2 qq = qbuf[i];
            float d = tp - qq.x;
            acc = fmaf(qq.y, fexp2(d * d * (-L2E)), acc);
        }
        acc *= mp;
        acc = wave_sum_shfl(acc);
        if ((tid & 63) == 0) atomicAdd(out, acc);
    }
}

// ll + le terms. Grid (32, 16): 32 p-chunks of 256 x 16 q-splits of 512.
__global__ __launch_bounds__(256) void ll_le(
    const float* __restrict__ texp,
    const float* __restrict__ tl,
    float* __restrict__ out)
{
    __shared__ __align__(16) float4 qbuf[512];
    __shared__ float red[4];

    const int pc = blockIdx.x;
    const int qs = blockIdx.y;
    const int tid = threadIdx.x;

    const int p = pc * 256 + tid;
    const float tlp = tl[p];
    const float mlp = (tlp < TMAXV && tlp > 0.0f) ? 1.0f : 0.0f;

    const int q0 = qs * 512;
    for (int i = tid; i < 512; i += 256) {
        float tq = tl[q0 + i];
        float mq = (tq < TMAXV && tq > 0.0f) ? 1.0f : 0.0f;
        float te = texp[q0 + i];
        float me = (te < TMAXV && te > 0.0f) ? 1.0f : 0.0f;
        qbuf[i] = make_float4(tq, mq, te, me);
    }
    __syncthreads();

    float val = 0.0f;
    // learner times are cumsum of Exp(1) increments: most p-points exceed T_MAX;
    // fully-masked waves skip the whole q-loop (wave-uniform branch).
    if (__ballot(mlp != 0.0f) != 0ULL) {
        float a_ll = 0.0f, a_le = 0.0f;
        #pragma unroll 4
        for (int i = 0; i < 512; ++i) {
            float4 q = qbuf[i];
            float d1 = tlp - q.x;
            a_ll = fmaf(q.y, fexp2(d1 * d1 * (-L2E)), a_ll);
            float d2 = tlp - q.z;
            a_le = fmaf(q.w, fexp2(d2 * d2 * (-L2E)), a_le);
        }
        val = mlp * (a_ll - 2.0f * a_le);
    }

    val = wave_sum_shfl(val);
    if ((tid & 63) == 0) red[tid >> 6] = val;
    __syncthreads();
    if (tid == 0) atomicAdd(out, red[0] + red[1] + red[2] + red[3]);
}

extern "C" void kernel_launch(void* const* d_in, const int* in_sizes, int n_in,
                              void* d_out, int out_size, void* d_ws, size_t ws_size,
                              hipStream_t stream) {
    const float* upool = (const float*)d_in[0];
    const float* texp  = (const float*)d_in[1];
    const float* Wih   = (const float*)d_in[2];
    const float* Whh   = (const float*)d_in[3];
    const float* bih   = (const float*)d_in[4];
    const float* bhh   = (const float*)d_in[5];
    const float* Vw    = (const float*)d_in[6];
    const float* Vb    = (const float*)d_in[7];
    float* out = (float*)d_out;
    float* tl  = (float*)d_ws;   // 8192 floats = 32 KB

    hipMemsetAsync(out, 0, sizeof(float), stream);
    hipLaunchKernelGGL(gen_and_ee, dim3(BATCH + 128), dim3(256), 0, stream,
                       upool, texp, Wih, Whh, bih, bhh, Vw, Vb, tl, out);
    hipLaunchKernelGGL(ll_le, dim3(32, 16), dim3(256), 0, stream, texp, tl, out);
}

// Round 13
// 157.072 us; speedup vs baseline: 1.4157x; 1.0126x over previous
//
#include <hip/hip_runtime.h>
#include <math.h>

#define HIDDEN 64
#define SEQ 128
#define BATCH 64
#define NPTS (BATCH * SEQ)   // 8192
#define TMAXV 20.0f
#define L2E 1.4426950408889634f
#define LN2 0.6931471805599453f

typedef float v2f __attribute__((ext_vector_type(2)));
typedef float v4f __attribute__((ext_vector_type(4)));   // asm-safe 128-bit tuple

__device__ __forceinline__ float fexp2(float x) { return __builtin_amdgcn_exp2f(x); }
__device__ __forceinline__ float flog2(float x) { return __builtin_amdgcn_logf(x); }
__device__ __forceinline__ float frcp(float x)  { return __builtin_amdgcn_rcpf(x); }
__device__ __forceinline__ float fsigmoid(float x) { return frcp(1.0f + fexp2(-x * L2E)); }
__device__ __forceinline__ float ftanh(float x)    { return 1.0f - 2.0f * frcp(1.0f + fexp2(2.0f * x * L2E)); }

// Raw barrier: orders LDS only (lgkmcnt), does NOT drain vmcnt.
__device__ __forceinline__ void barrier_lds_only() {
    asm volatile("s_waitcnt lgkmcnt(0)" ::: "memory");
    __builtin_amdgcn_s_barrier();
}

// ---- DPP wave64 sum: VALU-pipe cross-lane (no LDS round trips). Result uniform.
template <int CTRL>
__device__ __forceinline__ float dpp_mov(float x) {
    int r = __builtin_amdgcn_update_dpp(0, __float_as_int(x), CTRL, 0xf, 0xf, false);
    return __int_as_float(r);
}
__device__ __forceinline__ float wave_sum_dpp(float x) {
    x += dpp_mov<0x111>(x);   // row_shr:1
    x += dpp_mov<0x112>(x);   // row_shr:2
    x += dpp_mov<0x114>(x);   // row_shr:4
    x += dpp_mov<0x118>(x);   // row_shr:8  -> lane 16r+15 = row sum
    x += dpp_mov<0x142>(x);   // row_bcast:15
    x += dpp_mov<0x143>(x);   // row_bcast:31 -> lane 63 = total
    return __int_as_float(__builtin_amdgcn_readlane(__float_as_int(x), 63));
}

__device__ __forceinline__ float wave_sum_shfl(float v) {
    v += __shfl_xor(v, 1);  v += __shfl_xor(v, 2);  v += __shfl_xor(v, 4);
    v += __shfl_xor(v, 8);  v += __shfl_xor(v, 16); v += __shfl_xor(v, 32);
    return v;
}

// Blocks [0,64): LSTM rollout, one batch per block, 256 threads (thread j = gate-row j).
// r3 structure (67.7us) with weights loaded ONCE via asm-volatile
// global_load_dwordx4 into ext_vector v4f registers. Volatile-asm results are
// non-rematerializable (r12 proved every compiler-visible path gets remat'd
// back to the const global: VGPR stayed 52); ~130 VGPR total < 256 cap with
// __launch_bounds__(256,1) -> no spill. The 64 KB/step weight re-stream
// (~1000-1500 cy/step on every memory pipe, r3/r5/r6) drops to ZERO.
// ext_vector (not float4 struct) in asm constraints is the r7 compile fix.
// Blocks [64,192): expert-expert MMD term (r12-identical).
__global__ __launch_bounds__(256, 1) void gen_and_ee(
    const float* __restrict__ upool,   // [B,S]
    const float* __restrict__ texp,    // [B,S]
    const float* __restrict__ Wih,     // [256]
    const float* __restrict__ Whh,     // [256,64]
    const float* __restrict__ bih,     // [256]
    const float* __restrict__ bhh,     // [256]
    const float* __restrict__ Vw,      // [64]
    const float* __restrict__ Vb,      // [1]
    float* __restrict__ tl,            // [NPTS] workspace
    float* __restrict__ out)           // [1] loss accumulator
{
    // [0,4096)      qbuf float2[2048] (EE) / act_s[2][256] = floats [0,512) (LSTM)
    // [4096,4352)   hx_s[4][64]
    // [4352,4480)   lu_s[128]
    __shared__ __align__(16) float smem[4480];

    const int bid = blockIdx.x;
    const int tid = threadIdx.x;

    if (bid < BATCH) {
        const int h  = tid & 63;
        const int wv = tid >> 6;

        float* act  = smem;                     // [2][256]
        float* hx_s = smem + 4096 + wv * 64;    // this wave's replica
        float* lu_s = smem + 4352;

        // ---- W_hh row `tid` -> 64 VGPRs via volatile asm (non-remat) ----
        v4f wq0, wq1, wq2, wq3, wq4, wq5, wq6, wq7;
        v4f wq8, wq9, wq10, wq11, wq12, wq13, wq14, wq15;
        {
            const float* wrow = Whh + tid * 64;
#define WLOAD4(A, B, C, D, PTR)                                         \
            asm volatile(                                               \
                "global_load_dwordx4 %0, %4, off\n\t"                   \
                "global_load_dwordx4 %1, %4, off offset:16\n\t"         \
                "global_load_dwordx4 %2, %4, off offset:32\n\t"         \
                "global_load_dwordx4 %3, %4, off offset:48\n\t"         \
                "s_waitcnt vmcnt(0)"                                    \
                : "=&v"(A), "=&v"(B), "=&v"(C), "=&v"(D)                \
                : "v"(PTR) : "memory")
            WLOAD4(wq0,  wq1,  wq2,  wq3,  wrow);
            WLOAD4(wq4,  wq5,  wq6,  wq7,  wrow + 16);
            WLOAD4(wq8,  wq9,  wq10, wq11, wrow + 32);
            WLOAD4(wq12, wq13, wq14, wq15, wrow + 48);
#undef WLOAD4
        }
        // repack to v2f pairs, same pairing as r3's w2[] (bit-exact)
        v2f w2[32];
        {
            v4f wq[16] = {wq0, wq1, wq2, wq3, wq4, wq5, wq6, wq7,
                          wq8, wq9, wq10, wq11, wq12, wq13, wq14, wq15};
            #pragma unroll
            for (int k = 0; k < 16; ++k) {
                w2[2 * k]     = (v2f){wq[k][0], wq[k][1]};
                w2[2 * k + 1] = (v2f){wq[k][2], wq[k][3]};
            }
        }

        const float bias = bih[tid] + bhh[tid];
        const float wih  = Wih[tid];
        const float vw   = Vw[h];      // all waves: redundant sigma reduction
        const float vb   = Vb[0];

        if (tid < SEQ) lu_s[tid] = -flog2(upool[bid * SEQ + tid]) * LN2;
        hx_s[h] = 0.0f;                // every wave zeroes its own replica
        float cx = 0.0f;
        barrier_lds_only();

        // step 0: hx = 0 -> sigma = elu(Vb)+1 (uniform)
        float sg0 = (vb > 0.0f) ? (vb + 1.0f) : fexp2(vb * L2E);
        float cum = lu_s[0] * frcp(sg0);
        float keep = (tid == 0) ? cum : 0.0f;   // thread t keeps cum of step t

        #pragma unroll 1
        for (int s = 0; s < SEQ - 1; ++s) {
            // gate-row dot hx, from this wave's private replica (broadcast b128)
            const float4* h4 = (const float4*)(smem + 4096 + wv * 64);
            v2f a0 = {0.f, 0.f}, a1 = {0.f, 0.f}, a2 = {0.f, 0.f}, a3 = {0.f, 0.f};
            #pragma unroll
            for (int k = 0; k < 16; k += 2) {
                float4 va = h4[k];
                float4 vbq = h4[k + 1];
                a0 = a0 + w2[2 * k]     * (v2f){va.x, va.y};
                a1 = a1 + w2[2 * k + 1] * (v2f){va.z, va.w};
                a2 = a2 + w2[2 * k + 2] * (v2f){vbq.x, vbq.y};
                a3 = a3 + w2[2 * k + 3] * (v2f){vbq.z, vbq.w};
            }
            v2f aa = (a0 + a1) + (a2 + a3);
            float g = (aa.x + aa.y) + bias + cum * wih;
            float a = (wv == 2) ? ftanh(g) : fsigmoid(g);
            act[(s & 1) * 256 + tid] = a;
            barrier_lds_only();        // the ONLY barrier per step; no vmcnt drain

            // redundant cell update in every wave (bit-identical across waves)
            float ig = act[(s & 1) * 256 + h];
            float fg = act[(s & 1) * 256 + 64 + h];
            float gg = act[(s & 1) * 256 + 128 + h];
            float og = act[(s & 1) * 256 + 192 + h];
            cx = fg * cx + ig * gg;
            float hx = og * ftanh(cx);
            hx_s[h] = hx;              // own replica; in-wave lgkmcnt ordering only

            float tot = wave_sum_dpp(hx * vw);
            float xx  = tot + vb;
            float sg  = (xx > 0.0f) ? (xx + 1.0f) : fexp2(xx * L2E);
            cum += lu_s[s + 1] * frcp(sg);

            keep = (tid == s + 1) ? cum : keep;   // threads 128..255 never match
        }
        if (tid < SEQ) tl[bid * SEQ + tid] = keep;
    } else {
        // ---------------- expert-expert MMD term (r12-identical) ----------------
        const int eb = bid - BATCH;      // 0..127
        const int pc = eb & 31;          // p-chunk (256 points)
        const int qs = eb >> 5;          // q-split (2048 points)

        float2* qbuf = (float2*)smem;    // [2048]

        const int p = pc * 256 + tid;
        const float tp = texp[p];
        const float mp = (tp < TMAXV && tp > 0.0f) ? 1.0f : 0.0f;

        const int q0 = qs * 2048;
        for (int i = tid; i < 2048; i += 256) {
            float tq = texp[q0 + i];
            float mq = (tq < TMAXV && tq > 0.0f) ? 1.0f : 0.0f;
            qbuf[i] = make_float2(tq, mq);
        }
        __syncthreads();

        float acc = 0.0f;
        #pragma unroll 4
        for (int i = 0; i < 2048; ++i) {
            float2 qq = qbuf[i];
            float d = tp - qq.x;
            acc = fmaf(qq.y, fexp2(d * d * (-L2E)), acc);
        }
        acc *= mp;
        acc = wave_sum_shfl(acc);
        if ((tid & 63) == 0) atomicAdd(out, acc);
    }
}

// ll + le terms. Grid (32, 16): 32 p-chunks of 256 x 16 q-splits of 512.
__global__ __launch_bounds__(256) void ll_le(
    const float* __restrict__ texp,
    const float* __restrict__ tl,
    float* __restrict__ out)
{
    __shared__ __align__(16) float4 qbuf[512];
    __shared__ float red[4];

    const int pc = blockIdx.x;
    const int qs = blockIdx.y;
    const int tid = threadIdx.x;

    const int p = pc * 256 + tid;
    const float tlp = tl[p];
    const float mlp = (tlp < TMAXV && tlp > 0.0f) ? 1.0f : 0.0f;

    const int q0 = qs * 512;
    for (int i = tid; i < 512; i += 256) {
        float tq = tl[q0 + i];
        float mq = (tq < TMAXV && tq > 0.0f) ? 1.0f : 0.0f;
        float te = texp[q0 + i];
        float me = (te < TMAXV && te > 0.0f) ? 1.0f : 0.0f;
        qbuf[i] = make_float4(tq, mq, te, me);
    }
    __syncthreads();

    float val = 0.0f;
    // learner times are cumsum of Exp(1) increments: most p-points exceed T_MAX;
    // fully-masked waves skip the whole q-loop (wave-uniform branch).
    if (__ballot(mlp != 0.0f) != 0ULL) {
        float a_ll = 0.0f, a_le = 0.0f;
        #pragma unroll 4
        for (int i = 0; i < 512; ++i) {
            float4 q = qbuf[i];
            float d1 = tlp - q.x;
            a_ll = fmaf(q.y, fexp2(d1 * d1 * (-L2E)), a_ll);
            float d2 = tlp - q.z;
            a_le = fmaf(q.w, fexp2(d2 * d2 * (-L2E)), a_le);
        }
        val = mlp * (a_ll - 2.0f * a_le);
    }

    val = wave_sum_shfl(val);
    if ((tid & 63) == 0) red[tid >> 6] = val;
    __syncthreads();
    if (tid == 0) atomicAdd(out, red[0] + red[1] + red[2] + red[3]);
}

extern "C" void kernel_launch(void* const* d_in, const int* in_sizes, int n_in,
                              void* d_out, int out_size, void* d_ws, size_t ws_size,
                              hipStream_t stream) {
    const float* upool = (const float*)d_in[0];
    const float* texp  = (const float*)d_in[1];
    const float* Wih   = (const float*)d_in[2];
    const float* Whh   = (const float*)d_in[3];
    const float* bih   = (const float*)d_in[4];
    const float* bhh   = (const float*)d_in[5];
    const float* Vw    = (const float*)d_in[6];
    const float* Vb    = (const float*)d_in[7];
    float* out = (float*)d_out;
    float* tl  = (float*)d_ws;   // 8192 floats = 32 KB

    hipMemsetAsync(out, 0, sizeof(float), stream);
    hipLaunchKernelGGL(gen_and_ee, dim3(BATCH + 128), dim3(256), 0, stream,
                       upool, texp, Wih, Whh, bih, bhh, Vw, Vb, tl, out);
    hipLaunchKernelGGL(ll_le, dim3(32, 16), dim3(256), 0, stream, texp, tl, out);
}